// Round 1
// baseline (6879.429 us; speedup 1.0000x reference)
//
#include <hip/hip_runtime.h>

// ---------- types & helpers ----------
typedef __attribute__((ext_vector_type(8))) short v8s;           // 8 x bf16 (MFMA frag)
typedef __attribute__((ext_vector_type(4))) float v4f;           // MFMA acc
typedef __attribute__((ext_vector_type(8))) unsigned short v8u;
typedef __attribute__((ext_vector_type(4))) unsigned short v4u;

__device__ __forceinline__ float bf2f(unsigned short u) {
  unsigned int x = ((unsigned int)u) << 16;
  return __builtin_bit_cast(float, x);
}
__device__ __forceinline__ unsigned short f2bf(float f) {
  unsigned int x = __builtin_bit_cast(unsigned int, f);
  x = x + 0x7FFFu + ((x >> 16) & 1u);   // RNE
  return (unsigned short)(x >> 16);
}
__device__ __forceinline__ float sigm(float x) { return 1.f / (1.f + __expf(-x)); }
__device__ __forceinline__ float tanh_(float x) {
  x = fminf(fmaxf(x, -15.f), 15.f);
  float e = __expf(2.f * x);
  return (e - 1.f) / (e + 1.f);
}
__device__ __forceinline__ void gll16(const void* g, void* l) {
  __builtin_amdgcn_global_load_lds((const __attribute__((address_space(1))) void*)g,
                                   (__attribute__((address_space(3))) void*)l, 16, 0, 0);
}

// ---------- f32 -> bf16 convert ----------
__global__ void f2bf_kernel(const float* __restrict__ s, unsigned short* __restrict__ d, int n) {
  int i = (blockIdx.x * 256 + threadIdx.x) * 4;
  if (i + 3 < n) {
    v4f v = *(const v4f*)(s + i);
    v4u o;
    #pragma unroll
    for (int j = 0; j < 4; ++j) o[j] = f2bf(v[j]);
    *(v4u*)(d + i) = o;
  }
}

// ---------- inp [16][2048][512] f32 -> X0 [t*16+b][2048] bf16 ----------
__global__ void transpose_in(const float* __restrict__ inp, unsigned short* __restrict__ X0) {
  int bidx = blockIdx.x;               // 4096 blocks: b(16) x itile(32) x ttile(8)
  int b  = bidx >> 8;
  int i0 = ((bidx >> 3) & 31) << 6;
  int t0 = (bidx & 7) << 6;
  __shared__ float tile[64][65];
  const float* ib = inp + ((size_t)b * 2048 + i0) * 512 + t0;
  #pragma unroll 4
  for (int it = 0; it < 16; ++it) {
    int lin = it * 256 + threadIdx.x;
    int ii = lin >> 6, tt = lin & 63;
    tile[ii][tt] = ib[(size_t)ii * 512 + tt];
  }
  __syncthreads();
  #pragma unroll 4
  for (int it = 0; it < 16; ++it) {
    int lin = it * 256 + threadIdx.x;
    int tt = lin >> 6, ii = lin & 63;
    X0[((size_t)(t0 + tt) * 16 + b) * 2048 + i0 + ii] = f2bf(tile[ii][tt]);
  }
}

// ---------- GEMM: C[M,N] = A[M,K] * W[N,K]^T + bias ----------
// A,W bf16 row-major; C bf16 (SCATTER=0) or f32 scattered to [B,1024,T] (SCATTER=1).
// 128x128 tile, BK=64, 4 waves (2x2), XOR-swizzled LDS, global_load_lds staging.
template <int SCATTER>
__global__ __launch_bounds__(256, 2) void gemm_bt(
    const unsigned short* __restrict__ A, const unsigned short* __restrict__ W,
    const float* __restrict__ bias, unsigned short* __restrict__ C,
    float* __restrict__ Cf, int M, int N, int K) {
  __shared__ char lds[2][2][16384];    // [buf][A/B][128 rows x 128B]

  const int tid = threadIdx.x, lane = tid & 63, wv = tid >> 6;
  const int ntiles = N >> 7;
  const int nwg = gridDim.x;
  const int cpx = nwg >> 3;            // grid % 8 == 0 for all our launches
  int wgid = blockIdx.x;
  int swz = (wgid & 7) * cpx + (wgid >> 3);
  const int mt = swz / ntiles, nt = swz % ntiles;
  const int wrow = wv >> 1, wcol = wv & 1;

  const unsigned short* Abase = A + (size_t)(mt << 7) * K;
  const unsigned short* Wbase = W + (size_t)(nt << 7) * K;
  const int r8 = lane >> 3, q = lane & 7;
  const int srcoff = (q << 4) ^ (r8 << 4);   // swizzled source byte within 128B row

  auto stage = [&](int buf, int kt) {
    const char* As = (const char*)(Abase + (size_t)kt * 64);
    const char* Ws = (const char*)(Wbase + (size_t)kt * 64);
    #pragma unroll
    for (int p = 0; p < 4; ++p) {
      int row = (((wv << 2) + p) << 3) + r8;
      int chunk = ((wv << 2) + p) << 10;
      gll16(As + (size_t)row * K * 2 + srcoff, &lds[buf][0][chunk]);
      gll16(Ws + (size_t)row * K * 2 + srcoff, &lds[buf][1][chunk]);
    }
  };

  v4f acc[4][4] = {};
  const int nk = K >> 6;
  stage(0, 0);
  for (int kt = 0; kt < nk; ++kt) {
    __syncthreads();                       // buf(kt) staged; buf(kt^1) free
    if (kt + 1 < nk) stage((kt + 1) & 1, kt + 1);
    const char* la = &lds[kt & 1][0][0] + (((wrow << 6) + (lane & 15)) << 7);
    const char* lb = &lds[kt & 1][1][0] + (((wcol << 6) + (lane & 15)) << 7);
    const int kswz = (lane & 7) << 4;
    #pragma unroll
    for (int kk = 0; kk < 2; ++kk) {
      const int kb = ((kk << 6) + ((lane >> 4) << 4)) ^ kswz;
      v8s af[4], bf[4];
      #pragma unroll
      for (int mi = 0; mi < 4; ++mi) af[mi] = *(const v8s*)(la + (mi << 11) + kb);
      #pragma unroll
      for (int ni = 0; ni < 4; ++ni) bf[ni] = *(const v8s*)(lb + (ni << 11) + kb);
      #pragma unroll
      for (int mi = 0; mi < 4; ++mi)
        #pragma unroll
        for (int ni = 0; ni < 4; ++ni)
          acc[mi][ni] = __builtin_amdgcn_mfma_f32_16x16x32_bf16(af[mi], bf[ni], acc[mi][ni], 0, 0, 0);
    }
  }

  const int gm0 = (mt << 7) + (wrow << 6) + ((lane >> 4) << 2);
  const int gn0 = (nt << 7) + (wcol << 6) + (lane & 15);
  #pragma unroll
  for (int ni = 0; ni < 4; ++ni) {
    const int gn = gn0 + (ni << 4);
    const float bv = bias ? bias[gn] : 0.f;
    #pragma unroll
    for (int mi = 0; mi < 4; ++mi) {
      #pragma unroll
      for (int r = 0; r < 4; ++r) {
        const int gm = gm0 + (mi << 4) + r;
        float v = acc[mi][ni][r] + bv;
        if (SCATTER) {
          Cf[(size_t)(gm & 15) * (1024 * 512) + (size_t)gn * 512 + (gm >> 4)] = v;
        } else {
          C[(size_t)gm * N + gn] = f2bf(v);
        }
      }
    }
  }
}

// ---------- persistent bidirectional GRU recurrence (one layer) ----------
// 128 WGs: dir = bid&1, wg = bid>>1 owns hidden units [wg*16, wg*16+16).
// w_hh slice (48 rows x 1024, bf16, swizzled) resident in LDS for all 512 steps.
// Per step: each wave MFMAs a K-quarter of gh, LDS-reduce, gates, write h to Y,
// then device-scope spin barrier over the 64 WGs of this direction chain.
__global__ __launch_bounds__(256, 1) void gru_recur(
    const unsigned short* __restrict__ gx,   // [8192][6144] (dir-major gate cols)
    const float* __restrict__ w_hh,          // [2][3072][1024] f32
    const float* __restrict__ b_hh,          // [2][3072] f32
    unsigned short* __restrict__ Y,          // [8192][2048], dir d -> cols [d*1024, ...)
    int* __restrict__ ctr) {                 // [2][512] step counters (zeroed)
  const int bid = blockIdx.x;
  const int dir = bid & 1;
  const int wg  = bid >> 1;
  const int j0  = wg << 4;
  const int tid = threadIdx.x;
  const int lane = tid & 63, wv = tid >> 6;

  __shared__ unsigned short wsl[3][16][1024];   // 96 KB, swizzled rows
  __shared__ float red[4][3][16][17];           // cross-wave partials (+pad)
  __shared__ float bhs[48];

  // --- load + convert w_hh slice into LDS (one-time) ---
  for (int c = tid; c < 6144; c += 256) {       // 16B chunks: 48 rows x 128 chunks
    int row48 = c >> 7;
    int g = row48 >> 4, jj = row48 & 15;
    int q = c & 127;
    const float* src = w_hh + (((size_t)dir * 3072 + (size_t)g * 1024 + j0 + jj) << 10) + (q << 3);
    v8u v;
    #pragma unroll
    for (int i = 0; i < 8; ++i) v[i] = f2bf(src[i]);
    char* base = (char*)(&wsl[g][jj][0]);
    *(v8u*)(base + ((q << 4) ^ ((jj & 7) << 4))) = v;
  }
  if (tid < 48) bhs[tid] = b_hh[dir * 3072 + (tid >> 4) * 1024 + j0 + (tid & 15)];
  __syncthreads();

  const int b = tid >> 4, jj = tid & 15;
  const size_t ycol = (size_t)dir * 1024;
  const size_t gxc = (size_t)dir * 3072 + j0 + jj;
  float hcur = 0.f;                             // own h[b][j0+jj] stays in-register

  for (int s = 0; s < 512; ++s) {
    const int t  = dir ? (511 - s) : s;
    const int tp = dir ? (t + 1) : (t - 1);

    const size_t grow = (size_t)(t * 16 + b);
    float xr = bf2f(gx[grow * 6144 + gxc]);
    float xz = bf2f(gx[grow * 6144 + gxc + 1024]);
    float xn = bf2f(gx[grow * 6144 + gxc + 2048]);

    v4f a0 = {0.f, 0.f, 0.f, 0.f}, a1 = {0.f, 0.f, 0.f, 0.f}, a2 = {0.f, 0.f, 0.f, 0.f};
    if (s > 0) {
      const unsigned short* hrow =
          Y + (size_t)(tp * 16 + (lane & 15)) * 2048 + ycol + (wv << 8) + ((lane >> 4) << 3);
      v8s af[8];
      #pragma unroll
      for (int kk = 0; kk < 8; ++kk) af[kk] = *(const v8s*)(hrow + (kk << 5));
      const char* wb0 = (const char*)(&wsl[0][lane & 15][0]);
      const int swz = (lane & 7) << 4;
      #pragma unroll
      for (int kk = 0; kk < 8; ++kk) {
        const int kb = (((wv << 8) + (kk << 5) + ((lane >> 4) << 3)) << 1) ^ swz;
        v8s b0 = *(const v8s*)(wb0 + kb);
        v8s b1 = *(const v8s*)(wb0 + 32768 + kb);
        v8s b2 = *(const v8s*)(wb0 + 65536 + kb);
        a0 = __builtin_amdgcn_mfma_f32_16x16x32_bf16(af[kk], b0, a0, 0, 0, 0);
        a1 = __builtin_amdgcn_mfma_f32_16x16x32_bf16(af[kk], b1, a1, 0, 0, 0);
        a2 = __builtin_amdgcn_mfma_f32_16x16x32_bf16(af[kk], b2, a2, 0, 0, 0);
      }
    }
    {
      const int rr0 = (lane >> 4) << 2, cc = lane & 15;
      #pragma unroll
      for (int r = 0; r < 4; ++r) {
        red[wv][0][rr0 + r][cc] = a0[r];
        red[wv][1][rr0 + r][cc] = a1[r];
        red[wv][2][rr0 + r][cc] = a2[r];
      }
    }
    __syncthreads();
    float ghr = red[0][0][b][jj] + red[1][0][b][jj] + red[2][0][b][jj] + red[3][0][b][jj] + bhs[jj];
    float ghz = red[0][1][b][jj] + red[1][1][b][jj] + red[2][1][b][jj] + red[3][1][b][jj] + bhs[16 + jj];
    float ghn = red[0][2][b][jj] + red[1][2][b][jj] + red[2][2][b][jj] + red[3][2][b][jj] + bhs[32 + jj];
    float r_ = sigm(xr + ghr);
    float z_ = sigm(xz + ghz);
    float n_ = tanh_(xn + r_ * ghn);
    float h  = (1.f - z_) * n_ + z_ * hcur;
    hcur = h;
    Y[grow * 2048 + ycol + j0 + jj] = f2bf(h);

    asm volatile("s_waitcnt vmcnt(0)" ::: "memory");   // own store in L2
    __syncthreads();                                    // all WG stores in L2
    if (tid == 0) {
      int* cp = ctr + dir * 512 + s;
      __hip_atomic_fetch_add(cp, 1, __ATOMIC_RELEASE, __HIP_MEMORY_SCOPE_AGENT);  // wbl2
      while (__hip_atomic_load(cp, __ATOMIC_RELAXED, __HIP_MEMORY_SCOPE_AGENT) < 64)
        __builtin_amdgcn_s_sleep(2);
      __builtin_amdgcn_fence(__ATOMIC_ACQUIRE, "agent");                          // inv
    }
    __syncthreads();
  }
}

// ---------- launcher ----------
extern "C" void kernel_launch(void* const* d_in, const int* in_sizes, int n_in,
                              void* d_out, int out_size, void* d_ws, size_t ws_size,
                              hipStream_t stream) {
  const float* inp     = (const float*)d_in[0];
  const float* w_in    = (const float*)d_in[1];
  const float* b_in    = (const float*)d_in[2];
  const float* w_ih_l0 = (const float*)d_in[3];
  const float* w_hh_l0 = (const float*)d_in[4];
  const float* b_ih_l0 = (const float*)d_in[5];
  const float* b_hh_l0 = (const float*)d_in[6];
  const float* w_ih_l1 = (const float*)d_in[7];
  const float* w_hh_l1 = (const float*)d_in[8];
  const float* b_ih_l1 = (const float*)d_in[9];
  const float* b_hh_l1 = (const float*)d_in[10];
  const float* w_out   = (const float*)d_in[11];
  const float* b_out   = (const float*)d_in[12];

  char* ws = (char*)d_ws;
  size_t off = 0;
  auto carve = [&](size_t bytes) {
    char* p = ws + off;
    off += (bytes + 255) & ~(size_t)255;
    return p;
  };
  unsigned short* GX      = (unsigned short*)carve(8192ull * 6144 * 2);  // gates, both dirs
  unsigned short* X0      = (unsigned short*)carve(8192ull * 2048 * 2);  // x (bf16); reused as Y1
  unsigned short* XF      = (unsigned short*)carve(8192ull * 1024 * 2);  // after input proj
  unsigned short* Y0      = (unsigned short*)carve(8192ull * 2048 * 2);  // layer0 out
  unsigned short* w_in_b  = (unsigned short*)carve(1024ull * 2048 * 2);
  unsigned short* w_l0_b  = (unsigned short*)carve(6144ull * 1024 * 2);
  unsigned short* w_l1_b  = (unsigned short*)carve(6144ull * 2048 * 2);
  unsigned short* w_out_b = (unsigned short*)carve(1024ull * 2048 * 2);
  int* ctr                = (int*)carve(2048 * 4);
  unsigned short* Y1 = X0;

  hipMemsetAsync(ctr, 0, 2048 * 4, stream);

  f2bf_kernel<<<2097152 / 1024, 256, 0, stream>>>(w_in, w_in_b, 2097152);
  f2bf_kernel<<<6291456 / 1024, 256, 0, stream>>>(w_ih_l0, w_l0_b, 6291456);
  f2bf_kernel<<<12582912 / 1024, 256, 0, stream>>>(w_ih_l1, w_l1_b, 12582912);
  f2bf_kernel<<<2097152 / 1024, 256, 0, stream>>>(w_out, w_out_b, 2097152);

  transpose_in<<<4096, 256, 0, stream>>>(inp, X0);

  // x @ w_in^T + b_in -> XF [8192][1024]
  gemm_bt<0><<<512, 256, 0, stream>>>(X0, w_in_b, b_in, XF, nullptr, 8192, 1024, 2048);
  // layer0 gates: XF @ w_ih_l0^T + b_ih_l0 -> GX [8192][6144]
  gemm_bt<0><<<3072, 256, 0, stream>>>(XF, w_l0_b, b_ih_l0, GX, nullptr, 8192, 6144, 1024);
  gru_recur<<<128, 256, 0, stream>>>(GX, w_hh_l0, b_hh_l0, Y0, ctr);
  // layer1 gates: Y0 @ w_ih_l1^T + b_ih_l1 -> GX
  gemm_bt<0><<<3072, 256, 0, stream>>>(Y0, w_l1_b, b_ih_l1, GX, nullptr, 8192, 6144, 2048);
  gru_recur<<<128, 256, 0, stream>>>(GX, w_hh_l1, b_hh_l1, Y1, ctr + 1024);
  // out = Y1 @ w_out^T + b_out, scattered to [B,1024,T] f32
  gemm_bt<1><<<512, 256, 0, stream>>>(Y1, w_out_b, b_out, nullptr, (float*)d_out, 8192, 1024, 2048);
}

// Round 3
// 5862.436 us; speedup vs baseline: 1.1735x; 1.1735x over previous
//
#include <hip/hip_runtime.h>

// ---------- types & helpers ----------
typedef __attribute__((ext_vector_type(8))) short v8s;           // 8 x bf16 (MFMA frag)
typedef __attribute__((ext_vector_type(4))) float v4f;           // MFMA acc
typedef __attribute__((ext_vector_type(8))) unsigned short v8u;
typedef __attribute__((ext_vector_type(4))) unsigned short v4u;

__device__ __forceinline__ float bf2f(unsigned short u) {
  unsigned int x = ((unsigned int)u) << 16;
  return __builtin_bit_cast(float, x);
}
__device__ __forceinline__ unsigned short f2bf(float f) {
  unsigned int x = __builtin_bit_cast(unsigned int, f);
  x = x + 0x7FFFu + ((x >> 16) & 1u);   // RNE
  return (unsigned short)(x >> 16);
}
__device__ __forceinline__ float sigm(float x) { return 1.f / (1.f + __expf(-x)); }
__device__ __forceinline__ float tanh_(float x) {
  x = fminf(fmaxf(x, -15.f), 15.f);
  float e = __expf(2.f * x);
  return (e - 1.f) / (e + 1.f);
}
__device__ __forceinline__ void gll16(const void* g, void* l) {
  __builtin_amdgcn_global_load_lds((const __attribute__((address_space(1))) void*)g,
                                   (__attribute__((address_space(3))) void*)l, 16, 0, 0);
}

// --- system-coherent (Infinity-Cache-level) accesses: bypass per-XCD L2 ---
__device__ __forceinline__ void st_short_sys(void* p, unsigned int v) {
  asm volatile("global_store_short %0, %1, off sc0 sc1" :: "v"(p), "v"(v) : "memory");
}
__device__ __forceinline__ v8s ld_v8s_sys(const void* p) {
  v8s v;
  asm volatile("global_load_dwordx4 %0, %1, off sc0 sc1" : "=v"(v) : "v"(p) : "memory");
  return v;
}

// ---------- f32 -> bf16 convert ----------
__global__ void f2bf_kernel(const float* __restrict__ s, unsigned short* __restrict__ d, int n) {
  int i = (blockIdx.x * 256 + threadIdx.x) * 4;
  if (i + 3 < n) {
    v4f v = *(const v4f*)(s + i);
    v4u o;
    #pragma unroll
    for (int j = 0; j < 4; ++j) o[j] = f2bf(v[j]);
    *(v4u*)(d + i) = o;
  }
}

// ---------- inp [16][2048][512] f32 -> X0 [t*16+b][2048] bf16 ----------
__global__ void transpose_in(const float* __restrict__ inp, unsigned short* __restrict__ X0) {
  int bidx = blockIdx.x;               // 4096 blocks: b(16) x itile(32) x ttile(8)
  int b  = bidx >> 8;
  int i0 = ((bidx >> 3) & 31) << 6;
  int t0 = (bidx & 7) << 6;
  __shared__ float tile[64][65];
  const float* ib = inp + ((size_t)b * 2048 + i0) * 512 + t0;
  #pragma unroll 4
  for (int it = 0; it < 16; ++it) {
    int lin = it * 256 + threadIdx.x;
    int ii = lin >> 6, tt = lin & 63;
    tile[ii][tt] = ib[(size_t)ii * 512 + tt];
  }
  __syncthreads();
  #pragma unroll 4
  for (int it = 0; it < 16; ++it) {
    int lin = it * 256 + threadIdx.x;
    int tt = lin >> 6, ii = lin & 63;
    X0[((size_t)(t0 + tt) * 16 + b) * 2048 + i0 + ii] = f2bf(tile[ii][tt]);
  }
}

// ---------- GEMM: C[M,N] = A[M,K] * W[N,K]^T + bias ----------
template <int SCATTER>
__global__ __launch_bounds__(256, 2) void gemm_bt(
    const unsigned short* __restrict__ A, const unsigned short* __restrict__ W,
    const float* __restrict__ bias, unsigned short* __restrict__ C,
    float* __restrict__ Cf, int M, int N, int K) {
  __shared__ char lds[2][2][16384];    // [buf][A/B][128 rows x 128B]

  const int tid = threadIdx.x, lane = tid & 63, wv = tid >> 6;
  const int ntiles = N >> 7;
  const int nwg = gridDim.x;
  const int cpx = nwg >> 3;            // grid % 8 == 0 for all our launches
  int wgid = blockIdx.x;
  int swz = (wgid & 7) * cpx + (wgid >> 3);
  const int mt = swz / ntiles, nt = swz % ntiles;
  const int wrow = wv >> 1, wcol = wv & 1;

  const unsigned short* Abase = A + (size_t)(mt << 7) * K;
  const unsigned short* Wbase = W + (size_t)(nt << 7) * K;
  const int r8 = lane >> 3, q = lane & 7;
  const int srcoff = (q << 4) ^ (r8 << 4);   // swizzled source byte within 128B row

  auto stage = [&](int buf, int kt) {
    const char* As = (const char*)(Abase + (size_t)kt * 64);
    const char* Ws = (const char*)(Wbase + (size_t)kt * 64);
    #pragma unroll
    for (int p = 0; p < 4; ++p) {
      int row = (((wv << 2) + p) << 3) + r8;
      int chunk = ((wv << 2) + p) << 10;
      gll16(As + (size_t)row * K * 2 + srcoff, &lds[buf][0][chunk]);
      gll16(Ws + (size_t)row * K * 2 + srcoff, &lds[buf][1][chunk]);
    }
  };

  v4f acc[4][4] = {};
  const int nk = K >> 6;
  stage(0, 0);
  for (int kt = 0; kt < nk; ++kt) {
    __syncthreads();                       // buf(kt) staged; buf(kt^1) free
    if (kt + 1 < nk) stage((kt + 1) & 1, kt + 1);
    const char* la = &lds[kt & 1][0][0] + (((wrow << 6) + (lane & 15)) << 7);
    const char* lb = &lds[kt & 1][1][0] + (((wcol << 6) + (lane & 15)) << 7);
    const int kswz = (lane & 7) << 4;
    #pragma unroll
    for (int kk = 0; kk < 2; ++kk) {
      const int kb = ((kk << 6) + ((lane >> 4) << 4)) ^ kswz;
      v8s af[4], bf[4];
      #pragma unroll
      for (int mi = 0; mi < 4; ++mi) af[mi] = *(const v8s*)(la + (mi << 11) + kb);
      #pragma unroll
      for (int ni = 0; ni < 4; ++ni) bf[ni] = *(const v8s*)(lb + (ni << 11) + kb);
      #pragma unroll
      for (int mi = 0; mi < 4; ++mi)
        #pragma unroll
        for (int ni = 0; ni < 4; ++ni)
          acc[mi][ni] = __builtin_amdgcn_mfma_f32_16x16x32_bf16(af[mi], bf[ni], acc[mi][ni], 0, 0, 0);
    }
  }

  const int gm0 = (mt << 7) + (wrow << 6) + ((lane >> 4) << 2);
  const int gn0 = (nt << 7) + (wcol << 6) + (lane & 15);
  #pragma unroll
  for (int ni = 0; ni < 4; ++ni) {
    const int gn = gn0 + (ni << 4);
    const float bv = bias ? bias[gn] : 0.f;
    #pragma unroll
    for (int mi = 0; mi < 4; ++mi) {
      #pragma unroll
      for (int r = 0; r < 4; ++r) {
        const int gm = gm0 + (mi << 4) + r;
        float v = acc[mi][ni][r] + bv;
        if (SCATTER) {
          Cf[(size_t)(gm & 15) * (1024 * 512) + (size_t)gn * 512 + (gm >> 4)] = v;
        } else {
          C[(size_t)gm * N + gn] = f2bf(v);
        }
      }
    }
  }
}

// ---------- persistent bidirectional GRU recurrence (one layer) ----------
// 128 WGs: dir = bid&1, wg = bid>>1 owns hidden units [wg*16, wg*16+16).
// h exchange: sc0sc1 (IF-coherent) stores/loads, ordered by vmcnt(0).
// Barrier: per-WG monotonic flags; publish AND poll via relaxed agent-scope
// atomic RMW (fetch_add) -- RMWs execute at the device coherence point, so
// they are cross-XCD visible with NO wbl2/buffer_inv cache maintenance.
__global__ __launch_bounds__(256, 1) void gru_recur(
    const unsigned short* __restrict__ gx,   // [8192][6144] (dir-major gate cols)
    const float* __restrict__ w_hh,          // [2][3072][1024] f32
    const float* __restrict__ b_hh,          // [2][3072] f32
    unsigned short* __restrict__ Y,          // [8192][2048], dir d -> cols [d*1024, ...)
    int* __restrict__ flags) {               // [2][64] monotonic step flags (zeroed)
  const int bid = blockIdx.x;
  const int dir = bid & 1;
  const int wg  = bid >> 1;
  const int j0  = wg << 4;
  const int tid = threadIdx.x;
  const int lane = tid & 63, wv = tid >> 6;

  __shared__ unsigned short wsl[3][16][1024];   // 96 KB, swizzled rows
  __shared__ float red[4][3][16][17];           // cross-wave partials (+pad)
  __shared__ float bhs[48];

  int* const myflags = flags + dir * 64;

  // --- load + convert w_hh slice into LDS (one-time) ---
  for (int c = tid; c < 6144; c += 256) {       // 16B chunks: 48 rows x 128 chunks
    int row48 = c >> 7;
    int g = row48 >> 4, jj = row48 & 15;
    int q = c & 127;
    const float* src = w_hh + (((size_t)dir * 3072 + (size_t)g * 1024 + j0 + jj) << 10) + (q << 3);
    v8u v;
    #pragma unroll
    for (int i = 0; i < 8; ++i) v[i] = f2bf(src[i]);
    char* base = (char*)(&wsl[g][jj][0]);
    *(v8u*)(base + ((q << 4) ^ ((jj & 7) << 4))) = v;
  }
  if (tid < 48) bhs[tid] = b_hh[dir * 3072 + (tid >> 4) * 1024 + j0 + (tid & 15)];
  __syncthreads();

  const int b = tid >> 4, jj = tid & 15;
  const size_t ycol = (size_t)dir * 1024;
  const size_t gxc = (size_t)dir * 3072 + j0 + jj;
  float hcur = 0.f;                             // own h[b][j0+jj] stays in-register

  // opaque zero: prevents LLVM from folding fetch_add(0) into a plain
  // (L2-cacheable, potentially-stale) atomic load.
  int zero = 0;
  asm volatile("" : "+v"(zero));

  for (int s = 0; s < 512; ++s) {
    const int t  = dir ? (511 - s) : s;
    const int tp = dir ? (t + 1) : (t - 1);

    // wait until all 64 WGs of this direction finished step s-1
    if (s > 0 && wv == 0) {
      int iters = 0;
      for (;;) {
        int v = __hip_atomic_fetch_add(myflags + lane, zero, __ATOMIC_RELAXED,
                                       __HIP_MEMORY_SCOPE_AGENT);
        if (__all(v >= s)) break;
        __builtin_amdgcn_s_sleep(1);
        if (++iters > 3000) break;   // bounded escape hatch (measurable failure, no hang)
      }
    }
    __syncthreads();

    const size_t grow = (size_t)(t * 16 + b);
    float xr = bf2f(gx[grow * 6144 + gxc]);
    float xz = bf2f(gx[grow * 6144 + gxc + 1024]);
    float xn = bf2f(gx[grow * 6144 + gxc + 2048]);

    v4f a0 = {0.f, 0.f, 0.f, 0.f}, a1 = {0.f, 0.f, 0.f, 0.f}, a2 = {0.f, 0.f, 0.f, 0.f};
    if (s > 0) {
      const unsigned short* hrow =
          Y + (size_t)(tp * 16 + (lane & 15)) * 2048 + ycol + (wv << 8) + ((lane >> 4) << 3);
      v8s af[8];
      #pragma unroll
      for (int kk = 0; kk < 8; ++kk) af[kk] = ld_v8s_sys(hrow + (kk << 5));
      asm volatile("s_waitcnt vmcnt(0)" ::: "memory");
      __builtin_amdgcn_sched_barrier(0);
      const char* wb0 = (const char*)(&wsl[0][lane & 15][0]);
      const int swz = (lane & 7) << 4;
      #pragma unroll
      for (int kk = 0; kk < 8; ++kk) {
        const int kb = (((wv << 8) + (kk << 5) + ((lane >> 4) << 3)) << 1) ^ swz;
        v8s b0 = *(const v8s*)(wb0 + kb);
        v8s b1 = *(const v8s*)(wb0 + 32768 + kb);
        v8s b2 = *(const v8s*)(wb0 + 65536 + kb);
        a0 = __builtin_amdgcn_mfma_f32_16x16x32_bf16(af[kk], b0, a0, 0, 0, 0);
        a1 = __builtin_amdgcn_mfma_f32_16x16x32_bf16(af[kk], b1, a1, 0, 0, 0);
        a2 = __builtin_amdgcn_mfma_f32_16x16x32_bf16(af[kk], b2, a2, 0, 0, 0);
      }
    }
    {
      const int rr0 = (lane >> 4) << 2, cc = lane & 15;
      #pragma unroll
      for (int r = 0; r < 4; ++r) {
        red[wv][0][rr0 + r][cc] = a0[r];
        red[wv][1][rr0 + r][cc] = a1[r];
        red[wv][2][rr0 + r][cc] = a2[r];
      }
    }
    __syncthreads();
    float ghr = red[0][0][b][jj] + red[1][0][b][jj] + red[2][0][b][jj] + red[3][0][b][jj] + bhs[jj];
    float ghz = red[0][1][b][jj] + red[1][1][b][jj] + red[2][1][b][jj] + red[3][1][b][jj] + bhs[16 + jj];
    float ghn = red[0][2][b][jj] + red[1][2][b][jj] + red[2][2][b][jj] + red[3][2][b][jj] + bhs[32 + jj];
    float r_ = sigm(xr + ghr);
    float z_ = sigm(xz + ghz);
    float n_ = tanh_(xn + r_ * ghn);
    float h  = (1.f - z_) * n_ + z_ * hcur;
    hcur = h;

    // publish h for this step at the Infinity-Cache coherence point
    st_short_sys(Y + grow * 2048 + ycol + j0 + jj, (unsigned int)f2bf(h));
    asm volatile("s_waitcnt vmcnt(0)" ::: "memory");   // h store reached IF
    __syncthreads();                                    // whole WG's h visible
    if (tid == 0 && s < 511)
      __hip_atomic_fetch_add(myflags + wg, 1, __ATOMIC_RELAXED, __HIP_MEMORY_SCOPE_AGENT);
  }
}

// ---------- launcher ----------
extern "C" void kernel_launch(void* const* d_in, const int* in_sizes, int n_in,
                              void* d_out, int out_size, void* d_ws, size_t ws_size,
                              hipStream_t stream) {
  const float* inp     = (const float*)d_in[0];
  const float* w_in    = (const float*)d_in[1];
  const float* b_in    = (const float*)d_in[2];
  const float* w_ih_l0 = (const float*)d_in[3];
  const float* w_hh_l0 = (const float*)d_in[4];
  const float* b_ih_l0 = (const float*)d_in[5];
  const float* b_hh_l0 = (const float*)d_in[6];
  const float* w_ih_l1 = (const float*)d_in[7];
  const float* w_hh_l1 = (const float*)d_in[8];
  const float* b_ih_l1 = (const float*)d_in[9];
  const float* b_hh_l1 = (const float*)d_in[10];
  const float* w_out   = (const float*)d_in[11];
  const float* b_out   = (const float*)d_in[12];

  char* ws = (char*)d_ws;
  size_t off = 0;
  auto carve = [&](size_t bytes) {
    char* p = ws + off;
    off += (bytes + 255) & ~(size_t)255;
    return p;
  };
  unsigned short* GX      = (unsigned short*)carve(8192ull * 6144 * 2);  // gates, both dirs
  unsigned short* X0      = (unsigned short*)carve(8192ull * 2048 * 2);  // x (bf16); reused as Y1
  unsigned short* XF      = (unsigned short*)carve(8192ull * 1024 * 2);  // after input proj
  unsigned short* Y0      = (unsigned short*)carve(8192ull * 2048 * 2);  // layer0 out
  unsigned short* w_in_b  = (unsigned short*)carve(1024ull * 2048 * 2);
  unsigned short* w_l0_b  = (unsigned short*)carve(6144ull * 1024 * 2);
  unsigned short* w_l1_b  = (unsigned short*)carve(6144ull * 2048 * 2);
  unsigned short* w_out_b = (unsigned short*)carve(1024ull * 2048 * 2);
  int* flags              = (int*)carve(4 * 64 * 4);   // [layer][dir][64]
  unsigned short* Y1 = X0;

  hipMemsetAsync(flags, 0, 4 * 64 * 4, stream);

  f2bf_kernel<<<2097152 / 1024, 256, 0, stream>>>(w_in, w_in_b, 2097152);
  f2bf_kernel<<<6291456 / 1024, 256, 0, stream>>>(w_ih_l0, w_l0_b, 6291456);
  f2bf_kernel<<<12582912 / 1024, 256, 0, stream>>>(w_ih_l1, w_l1_b, 12582912);
  f2bf_kernel<<<2097152 / 1024, 256, 0, stream>>>(w_out, w_out_b, 2097152);

  transpose_in<<<4096, 256, 0, stream>>>(inp, X0);

  // x @ w_in^T + b_in -> XF [8192][1024]
  gemm_bt<0><<<512, 256, 0, stream>>>(X0, w_in_b, b_in, XF, nullptr, 8192, 1024, 2048);
  // layer0 gates: XF @ w_ih_l0^T + b_ih_l0 -> GX [8192][6144]
  gemm_bt<0><<<3072, 256, 0, stream>>>(XF, w_l0_b, b_ih_l0, GX, nullptr, 8192, 6144, 1024);
  gru_recur<<<128, 256, 0, stream>>>(GX, w_hh_l0, b_hh_l0, Y0, flags);
  // layer1 gates: Y0 @ w_ih_l1^T + b_ih_l1 -> GX
  gemm_bt<0><<<3072, 256, 0, stream>>>(Y0, w_l1_b, b_ih_l1, GX, nullptr, 8192, 6144, 2048);
  gru_recur<<<128, 256, 0, stream>>>(GX, w_hh_l1, b_hh_l1, Y1, flags + 128);
  // out = Y1 @ w_out^T + b_out, scattered to [B,1024,T] f32
  gemm_bt<1><<<512, 256, 0, stream>>>(Y1, w_out_b, b_out, nullptr, (float*)d_out, 8192, 1024, 2048);
}

// Round 4
// 5096.272 us; speedup vs baseline: 1.3499x; 1.1503x over previous
//
#include <hip/hip_runtime.h>

// ---------- types & helpers ----------
typedef __attribute__((ext_vector_type(8))) short v8s;           // 8 x bf16 (MFMA frag)
typedef __attribute__((ext_vector_type(4))) float v4f;           // MFMA acc
typedef __attribute__((ext_vector_type(8))) unsigned short v8u;
typedef __attribute__((ext_vector_type(4))) unsigned short v4u;

__device__ __forceinline__ float bf2f(unsigned short u) {
  unsigned int x = ((unsigned int)u) << 16;
  return __builtin_bit_cast(float, x);
}
__device__ __forceinline__ unsigned short f2bf(float f) {
  unsigned int x = __builtin_bit_cast(unsigned int, f);
  x = x + 0x7FFFu + ((x >> 16) & 1u);   // RNE
  return (unsigned short)(x >> 16);
}
__device__ __forceinline__ float sigm(float x) { return 1.f / (1.f + __expf(-x)); }
__device__ __forceinline__ float tanh_(float x) {
  x = fminf(fmaxf(x, -15.f), 15.f);
  float e = __expf(2.f * x);
  return (e - 1.f) / (e + 1.f);
}
__device__ __forceinline__ void gll16(const void* g, void* l) {
  __builtin_amdgcn_global_load_lds((const __attribute__((address_space(1))) void*)g,
                                   (__attribute__((address_space(3))) void*)l, 16, 0, 0);
}

// --- system-coherent (Infinity-Cache-level) accesses: bypass per-XCD L2 ---
__device__ __forceinline__ void st_short_sys(void* p, unsigned int v) {
  asm volatile("global_store_short %0, %1, off sc0 sc1" :: "v"(p), "v"(v) : "memory");
}
__device__ __forceinline__ void st_int_sys(void* p, int v) {
  asm volatile("global_store_dword %0, %1, off sc0 sc1" :: "v"(p), "v"(v) : "memory");
}
__device__ __forceinline__ int ld_int_sys(const void* p) {
  int v;
  asm volatile("global_load_dword %0, %1, off sc0 sc1" : "=v"(v) : "v"(p) : "memory");
  asm volatile("s_waitcnt vmcnt(0)" ::: "memory");
  return v;
}
__device__ __forceinline__ v8s ld_v8s_sys(const void* p) {
  v8s v;
  asm volatile("global_load_dwordx4 %0, %1, off sc0 sc1" : "=v"(v) : "v"(p) : "memory");
  return v;
}

// ---------- f32 -> bf16 convert ----------
__global__ void f2bf_kernel(const float* __restrict__ s, unsigned short* __restrict__ d, int n) {
  int i = (blockIdx.x * 256 + threadIdx.x) * 4;
  if (i + 3 < n) {
    v4f v = *(const v4f*)(s + i);
    v4u o;
    #pragma unroll
    for (int j = 0; j < 4; ++j) o[j] = f2bf(v[j]);
    *(v4u*)(d + i) = o;
  }
}

// ---------- inp [16][2048][512] f32 -> X0 [t*16+b][2048] bf16 ----------
__global__ void transpose_in(const float* __restrict__ inp, unsigned short* __restrict__ X0) {
  int bidx = blockIdx.x;               // 4096 blocks: b(16) x itile(32) x ttile(8)
  int b  = bidx >> 8;
  int i0 = ((bidx >> 3) & 31) << 6;
  int t0 = (bidx & 7) << 6;
  __shared__ float tile[64][65];
  const float* ib = inp + ((size_t)b * 2048 + i0) * 512 + t0;
  #pragma unroll 4
  for (int it = 0; it < 16; ++it) {
    int lin = it * 256 + threadIdx.x;
    int ii = lin >> 6, tt = lin & 63;
    tile[ii][tt] = ib[(size_t)ii * 512 + tt];
  }
  __syncthreads();
  #pragma unroll 4
  for (int it = 0; it < 16; ++it) {
    int lin = it * 256 + threadIdx.x;
    int tt = lin >> 6, ii = lin & 63;
    X0[((size_t)(t0 + tt) * 16 + b) * 2048 + i0 + ii] = f2bf(tile[ii][tt]);
  }
}

// ---------- GEMM: C[M,N] = A[M,K] * W[N,K]^T + bias ----------
template <int SCATTER>
__global__ __launch_bounds__(256, 2) void gemm_bt(
    const unsigned short* __restrict__ A, const unsigned short* __restrict__ W,
    const float* __restrict__ bias, unsigned short* __restrict__ C,
    float* __restrict__ Cf, int M, int N, int K) {
  __shared__ char lds[2][2][16384];    // [buf][A/B][128 rows x 128B]

  const int tid = threadIdx.x, lane = tid & 63, wv = tid >> 6;
  const int ntiles = N >> 7;
  const int nwg = gridDim.x;
  const int cpx = nwg >> 3;            // grid % 8 == 0 for all our launches
  int wgid = blockIdx.x;
  int swz = (wgid & 7) * cpx + (wgid >> 3);
  const int mt = swz / ntiles, nt = swz % ntiles;
  const int wrow = wv >> 1, wcol = wv & 1;

  const unsigned short* Abase = A + (size_t)(mt << 7) * K;
  const unsigned short* Wbase = W + (size_t)(nt << 7) * K;
  const int r8 = lane >> 3, q = lane & 7;
  const int srcoff = (q << 4) ^ (r8 << 4);   // swizzled source byte within 128B row

  auto stage = [&](int buf, int kt) {
    const char* As = (const char*)(Abase + (size_t)kt * 64);
    const char* Ws = (const char*)(Wbase + (size_t)kt * 64);
    #pragma unroll
    for (int p = 0; p < 4; ++p) {
      int row = (((wv << 2) + p) << 3) + r8;
      int chunk = ((wv << 2) + p) << 10;
      gll16(As + (size_t)row * K * 2 + srcoff, &lds[buf][0][chunk]);
      gll16(Ws + (size_t)row * K * 2 + srcoff, &lds[buf][1][chunk]);
    }
  };

  v4f acc[4][4] = {};
  const int nk = K >> 6;
  stage(0, 0);
  for (int kt = 0; kt < nk; ++kt) {
    __syncthreads();                       // buf(kt) staged; buf(kt^1) free
    if (kt + 1 < nk) stage((kt + 1) & 1, kt + 1);
    const char* la = &lds[kt & 1][0][0] + (((wrow << 6) + (lane & 15)) << 7);
    const char* lb = &lds[kt & 1][1][0] + (((wcol << 6) + (lane & 15)) << 7);
    const int kswz = (lane & 7) << 4;
    #pragma unroll
    for (int kk = 0; kk < 2; ++kk) {
      const int kb = ((kk << 6) + ((lane >> 4) << 4)) ^ kswz;
      v8s af[4], bf[4];
      #pragma unroll
      for (int mi = 0; mi < 4; ++mi) af[mi] = *(const v8s*)(la + (mi << 11) + kb);
      #pragma unroll
      for (int ni = 0; ni < 4; ++ni) bf[ni] = *(const v8s*)(lb + (ni << 11) + kb);
      #pragma unroll
      for (int mi = 0; mi < 4; ++mi)
        #pragma unroll
        for (int ni = 0; ni < 4; ++ni)
          acc[mi][ni] = __builtin_amdgcn_mfma_f32_16x16x32_bf16(af[mi], bf[ni], acc[mi][ni], 0, 0, 0);
    }
  }

  const int gm0 = (mt << 7) + (wrow << 6) + ((lane >> 4) << 2);
  const int gn0 = (nt << 7) + (wcol << 6) + (lane & 15);
  #pragma unroll
  for (int ni = 0; ni < 4; ++ni) {
    const int gn = gn0 + (ni << 4);
    const float bv = bias ? bias[gn] : 0.f;
    #pragma unroll
    for (int mi = 0; mi < 4; ++mi) {
      #pragma unroll
      for (int r = 0; r < 4; ++r) {
        const int gm = gm0 + (mi << 4) + r;
        float v = acc[mi][ni][r] + bv;
        if (SCATTER) {
          Cf[(size_t)(gm & 15) * (1024 * 512) + (size_t)gn * 512 + (gm >> 4)] = v;
        } else {
          C[(size_t)gm * N + gn] = f2bf(v);
        }
      }
    }
  }
}

// ---------- persistent bidirectional GRU recurrence (one layer) ----------
// 128 WGs: dir = bid&1, wg = bid>>1 owns hidden units [wg*16, wg*16+16).
// h exchange AND flags: plain sc0sc1 (IF-coherent) stores/loads, ordered by
// vmcnt(0) + __syncthreads. NO atomics, NO RMW serialization, NO cache ops.
// Wave wv consumes h cols [wv*256, wv*256+256) = producers 16wv..16wv+15, so
// each wave polls only its own 16 producer flags (coalesced 64B load).
__global__ __launch_bounds__(256, 1) void gru_recur(
    const unsigned short* __restrict__ gx,   // [8192][6144] (dir-major gate cols)
    const float* __restrict__ w_hh,          // [2][3072][1024] f32
    const float* __restrict__ b_hh,          // [2][3072] f32
    unsigned short* __restrict__ Y,          // [8192][2048], dir d -> cols [d*1024, ...)
    int* __restrict__ flags) {               // [2][64] monotonic step flags (zeroed)
  const int bid = blockIdx.x;
  const int dir = bid & 1;
  const int wg  = bid >> 1;
  const int j0  = wg << 4;
  const int tid = threadIdx.x;
  const int lane = tid & 63, wv = tid >> 6;

  __shared__ unsigned short wsl[3][16][1024];   // 96 KB, swizzled rows
  __shared__ float red[4][3][16][17];           // cross-wave partials (+pad)
  __shared__ float bhs[48];

  int* const myflags = flags + dir * 64;

  // --- load + convert w_hh slice into LDS (one-time) ---
  for (int c = tid; c < 6144; c += 256) {       // 16B chunks: 48 rows x 128 chunks
    int row48 = c >> 7;
    int g = row48 >> 4, jj = row48 & 15;
    int q = c & 127;
    const float* src = w_hh + (((size_t)dir * 3072 + (size_t)g * 1024 + j0 + jj) << 10) + (q << 3);
    v8u v;
    #pragma unroll
    for (int i = 0; i < 8; ++i) v[i] = f2bf(src[i]);
    char* base = (char*)(&wsl[g][jj][0]);
    *(v8u*)(base + ((q << 4) ^ ((jj & 7) << 4))) = v;
  }
  if (tid < 48) bhs[tid] = b_hh[dir * 3072 + (tid >> 4) * 1024 + j0 + (tid & 15)];
  __syncthreads();

  const int b = tid >> 4, jj = tid & 15;
  const size_t ycol = (size_t)dir * 1024;
  const size_t gxc = (size_t)dir * 3072 + j0 + jj;
  float hcur = 0.f;                             // own h[b][j0+jj] stays in-register

  // this wave's producer-flag slot (16 flags, replicated 4x across 64 lanes)
  const int* const fp = myflags + ((wv << 4) + (lane & 15));

  // preload gx for step 0
  float xr, xz, xn;
  {
    const int t0i = dir ? 511 : 0;
    const size_t g0 = (size_t)(t0i * 16 + b) * 6144 + gxc;
    xr = bf2f(gx[g0]);
    xz = bf2f(gx[g0 + 1024]);
    xn = bf2f(gx[g0 + 2048]);
  }

  for (int s = 0; s < 512; ++s) {
    const int t  = dir ? (511 - s) : s;
    const int tp = dir ? (t + 1) : (t - 1);

    // per-wave: wait until THIS wave's 16 producer WGs finished step s-1
    if (s > 0) {
      int iters = 0;
      for (;;) {
        int v = ld_int_sys(fp);
        if (__all(v >= s)) break;
        __builtin_amdgcn_s_sleep(1);
        if (++iters > 2000) break;   // bounded escape hatch (measurable, no hang)
      }
    }

    v4f a0 = {0.f, 0.f, 0.f, 0.f}, a1 = {0.f, 0.f, 0.f, 0.f}, a2 = {0.f, 0.f, 0.f, 0.f};
    if (s > 0) {
      const unsigned short* hrow =
          Y + (size_t)(tp * 16 + (lane & 15)) * 2048 + ycol + (wv << 8) + ((lane >> 4) << 3);
      v8s af[8];
      #pragma unroll
      for (int kk = 0; kk < 8; ++kk) af[kk] = ld_v8s_sys(hrow + (kk << 5));
      asm volatile("s_waitcnt vmcnt(0)" ::: "memory");
      __builtin_amdgcn_sched_barrier(0);
      const char* wb0 = (const char*)(&wsl[0][lane & 15][0]);
      const int swz = (lane & 7) << 4;
      #pragma unroll
      for (int kk = 0; kk < 8; ++kk) {
        const int kb = (((wv << 8) + (kk << 5) + ((lane >> 4) << 3)) << 1) ^ swz;
        v8s b0 = *(const v8s*)(wb0 + kb);
        v8s b1 = *(const v8s*)(wb0 + 32768 + kb);
        v8s b2 = *(const v8s*)(wb0 + 65536 + kb);
        a0 = __builtin_amdgcn_mfma_f32_16x16x32_bf16(af[kk], b0, a0, 0, 0, 0);
        a1 = __builtin_amdgcn_mfma_f32_16x16x32_bf16(af[kk], b1, a1, 0, 0, 0);
        a2 = __builtin_amdgcn_mfma_f32_16x16x32_bf16(af[kk], b2, a2, 0, 0, 0);
      }
    }
    {
      const int rr0 = (lane >> 4) << 2, cc = lane & 15;
      #pragma unroll
      for (int r = 0; r < 4; ++r) {
        red[wv][0][rr0 + r][cc] = a0[r];
        red[wv][1][rr0 + r][cc] = a1[r];
        red[wv][2][rr0 + r][cc] = a2[r];
      }
    }
    __syncthreads();
    float ghr = red[0][0][b][jj] + red[1][0][b][jj] + red[2][0][b][jj] + red[3][0][b][jj] + bhs[jj];
    float ghz = red[0][1][b][jj] + red[1][1][b][jj] + red[2][1][b][jj] + red[3][1][b][jj] + bhs[16 + jj];
    float ghn = red[0][2][b][jj] + red[1][2][b][jj] + red[2][2][b][jj] + red[3][2][b][jj] + bhs[32 + jj];
    float r_ = sigm(xr + ghr);
    float z_ = sigm(xz + ghz);
    float n_ = tanh_(xn + r_ * ghn);
    float h  = (1.f - z_) * n_ + z_ * hcur;
    hcur = h;

    // prefetch next step's gx while the h store drains (independent loads)
    float nxr = 0.f, nxz = 0.f, nxn = 0.f;
    if (s < 511) {
      const int tn = dir ? (510 - s) : (s + 1);
      const size_t gn = (size_t)(tn * 16 + b) * 6144 + gxc;
      nxr = bf2f(gx[gn]);
      nxz = bf2f(gx[gn + 1024]);
      nxn = bf2f(gx[gn + 2048]);
    }

    // publish h at the Infinity-Cache coherence point
    st_short_sys(Y + (size_t)(t * 16 + b) * 2048 + ycol + j0 + jj, (unsigned int)f2bf(h));
    asm volatile("s_waitcnt vmcnt(0)" ::: "memory");   // h store reached IF
    __syncthreads();                                    // whole WG's h visible
    if (tid == 0 && s < 511)
      st_int_sys(myflags + wg, s + 1);                  // plain coherent flag store

    xr = nxr; xz = nxz; xn = nxn;
  }
}

// ---------- launcher ----------
extern "C" void kernel_launch(void* const* d_in, const int* in_sizes, int n_in,
                              void* d_out, int out_size, void* d_ws, size_t ws_size,
                              hipStream_t stream) {
  const float* inp     = (const float*)d_in[0];
  const float* w_in    = (const float*)d_in[1];
  const float* b_in    = (const float*)d_in[2];
  const float* w_ih_l0 = (const float*)d_in[3];
  const float* w_hh_l0 = (const float*)d_in[4];
  const float* b_ih_l0 = (const float*)d_in[5];
  const float* b_hh_l0 = (const float*)d_in[6];
  const float* w_ih_l1 = (const float*)d_in[7];
  const float* w_hh_l1 = (const float*)d_in[8];
  const float* b_ih_l1 = (const float*)d_in[9];
  const float* b_hh_l1 = (const float*)d_in[10];
  const float* w_out   = (const float*)d_in[11];
  const float* b_out   = (const float*)d_in[12];

  char* ws = (char*)d_ws;
  size_t off = 0;
  auto carve = [&](size_t bytes) {
    char* p = ws + off;
    off += (bytes + 255) & ~(size_t)255;
    return p;
  };
  unsigned short* GX      = (unsigned short*)carve(8192ull * 6144 * 2);  // gates, both dirs
  unsigned short* X0      = (unsigned short*)carve(8192ull * 2048 * 2);  // x (bf16); reused as Y1
  unsigned short* XF      = (unsigned short*)carve(8192ull * 1024 * 2);  // after input proj
  unsigned short* Y0      = (unsigned short*)carve(8192ull * 2048 * 2);  // layer0 out
  unsigned short* w_in_b  = (unsigned short*)carve(1024ull * 2048 * 2);
  unsigned short* w_l0_b  = (unsigned short*)carve(6144ull * 1024 * 2);
  unsigned short* w_l1_b  = (unsigned short*)carve(6144ull * 2048 * 2);
  unsigned short* w_out_b = (unsigned short*)carve(1024ull * 2048 * 2);
  int* flags              = (int*)carve(4 * 64 * 4);   // [layer][dir][64]
  unsigned short* Y1 = X0;

  hipMemsetAsync(flags, 0, 4 * 64 * 4, stream);

  f2bf_kernel<<<2097152 / 1024, 256, 0, stream>>>(w_in, w_in_b, 2097152);
  f2bf_kernel<<<6291456 / 1024, 256, 0, stream>>>(w_ih_l0, w_l0_b, 6291456);
  f2bf_kernel<<<12582912 / 1024, 256, 0, stream>>>(w_ih_l1, w_l1_b, 12582912);
  f2bf_kernel<<<2097152 / 1024, 256, 0, stream>>>(w_out, w_out_b, 2097152);

  transpose_in<<<4096, 256, 0, stream>>>(inp, X0);

  // x @ w_in^T + b_in -> XF [8192][1024]
  gemm_bt<0><<<512, 256, 0, stream>>>(X0, w_in_b, b_in, XF, nullptr, 8192, 1024, 2048);
  // layer0 gates: XF @ w_ih_l0^T + b_ih_l0 -> GX [8192][6144]
  gemm_bt<0><<<3072, 256, 0, stream>>>(XF, w_l0_b, b_ih_l0, GX, nullptr, 8192, 6144, 1024);
  gru_recur<<<128, 256, 0, stream>>>(GX, w_hh_l0, b_hh_l0, Y0, flags);
  // layer1 gates: Y0 @ w_ih_l1^T + b_ih_l1 -> GX
  gemm_bt<0><<<3072, 256, 0, stream>>>(Y0, w_l1_b, b_ih_l1, GX, nullptr, 8192, 6144, 2048);
  gru_recur<<<128, 256, 0, stream>>>(GX, w_hh_l1, b_hh_l1, Y1, flags + 128);
  // out = Y1 @ w_out^T + b_out, scattered to [B,1024,T] f32
  gemm_bt<1><<<512, 256, 0, stream>>>(Y1, w_out_b, b_out, nullptr, (float*)d_out, 8192, 1024, 2048);
}